// Round 5
// baseline (464.204 us; speedup 1.0000x reference)
//
#include <hip/hip_runtime.h>

// ---- problem constants ----
#define BSZ 4
#define SEQ 2048
#define DIM 1024
#define NH  16
#define HD  64
#define QT  128   // q rows per block pass (flash)
#define KT  64    // kv rows per tile (flash)
#define PAD 72    // u16 row stride in flash epilogue LDS

typedef float v4f __attribute__((ext_vector_type(4)));
typedef short s8v __attribute__((ext_vector_type(8)));
typedef unsigned short u16;
typedef unsigned short u16x8 __attribute__((ext_vector_type(8)));
typedef unsigned short u16x4 __attribute__((ext_vector_type(4)));
typedef unsigned int u32;
typedef unsigned int u32x4 __attribute__((ext_vector_type(4)));

__device__ __forceinline__ u16 f2bf(float f) {
  u32 u = __builtin_bit_cast(u32, f);
  u32 r = u + 0x7fffu + ((u >> 16) & 1u);  // RNE
  return (u16)(r >> 16);
}
__device__ __forceinline__ float bf2f(u16 h) {
  return __builtin_bit_cast(float, (u32)h << 16);
}
__device__ __forceinline__ float fast_exp2(float x) {
#if __has_builtin(__builtin_amdgcn_exp2f)
  return __builtin_amdgcn_exp2f(x);
#else
  return exp2f(x);
#endif
}
// pack two fp32 -> two trunc-bf16 in one v_perm_b32: low16 = bf(lo), high16 = bf(hi)
__device__ __forceinline__ u32 pk2(float hi, float lo) {
  return __builtin_amdgcn_perm(__builtin_bit_cast(u32, hi),
                               __builtin_bit_cast(u32, lo), 0x07060302u);
}

// ---------------- cast x (fp32) -> bf16 ----------------
__global__ __launch_bounds__(256) void cast_bf16_kernel(const float* __restrict__ x,
                                                        u16* __restrict__ o, int n4) {
  int i = blockIdx.x * 256 + threadIdx.x;
  if (i >= n4) return;
  v4f v = reinterpret_cast<const v4f*>(x)[i];
  u16x4 r;
  #pragma unroll
  for (int c = 0; c < 4; c++) r[c] = f2bf(v[c]);
  reinterpret_cast<u16x4*>(o)[i] = r;
}

// ---------------- transpose + cast W[k][n] -> Wt[n][k] bf16 ----------------
// z==0 (Wq) additionally folds in the attention scale 1/sqrt(HD)*log2(e), so Q
// comes out of the QKV GEMM pre-scaled for the exp2-domain softmax.
__global__ __launch_bounds__(256) void transpose_cast_kernel(const float* __restrict__ W0,
                                                             const float* __restrict__ W1,
                                                             const float* __restrict__ W2,
                                                             const float* __restrict__ W3,
                                                             u16* __restrict__ out) {
  const float* W = blockIdx.z == 0 ? W0 : blockIdx.z == 1 ? W1 : blockIdx.z == 2 ? W2 : W3;
  const float scale = (blockIdx.z == 0) ? 0.18033688011112042f : 1.0f;
  u16* T = out + (size_t)blockIdx.z * DIM * DIM;
  __shared__ float tile[32][33];
  int tx = threadIdx.x & 31, ty = threadIdx.x >> 5;
  int bn = blockIdx.x * 32, bk = blockIdx.y * 32;
  #pragma unroll
  for (int r = 0; r < 4; r++) {
    int k = bk + ty + r * 8;
    tile[ty + r * 8][tx] = W[(size_t)k * DIM + bn + tx];
  }
  __syncthreads();
  #pragma unroll
  for (int r = 0; r < 4; r++) {
    int n = bn + ty + r * 8;
    T[(size_t)n * DIM + bk + tx] = f2bf(tile[tx][ty + r * 8] * scale);
  }
}

// ======== direct-to-register GEMM core (128x128 tile, no LDS, no barriers) ========
// MFMA fragments are 16 contiguous bytes per lane, so load them straight from
// global (L2-hot): A row m0+waveM*64+i*16+l16, k-offset quad*8. The HW scoreboard
// pipelines loads across K-iterations -- no vmcnt(0) barrier drain.
// XCD swizzle: flat = x + 8y; xcd = flat&7 owns an 8-panel M-slab x all N
// -> per-XCD L2 working set ~ 2MB A-slab + 2MB W.

#define GEMM_SETUP_AND_LOOP()                                                    \
  const int flat = blockIdx.x + 8 * blockIdx.y;                                  \
  const int xcd = flat & 7, slot = flat >> 3;                                    \
  const int m0 = (xcd * 8 + (slot & 7)) * 128;                                   \
  const int n0 = (slot >> 3) * 128;                                              \
  const int t = threadIdx.x;                                                     \
  const int lane = t & 63;                                                       \
  const int waveM = (t >> 6) >> 1, waveN = (t >> 6) & 1;                         \
  const int quad = lane >> 4, l16 = lane & 15;                                   \
  v4f acc[4][4];                                                                 \
  _Pragma("unroll") for (int i = 0; i < 4; i++)                                  \
    _Pragma("unroll") for (int j = 0; j < 4; j++)                                \
      acc[i][j] = (v4f){0.f, 0.f, 0.f, 0.f};                                     \
  const u16* Ar[4];                                                              \
  const u16* Br[4];                                                              \
  _Pragma("unroll") for (int i = 0; i < 4; i++)                                  \
    Ar[i] = A + (size_t)(m0 + waveM * 64 + i * 16 + l16) * DIM + quad * 8;       \
  _Pragma("unroll") for (int j = 0; j < 4; j++)                                  \
    Br[j] = Bt + (size_t)(n0 + waveN * 64 + j * 16 + l16) * DIM + quad * 8;      \
  _Pragma("unroll 4") for (int k0 = 0; k0 < DIM; k0 += 32) {                     \
    s8v af[4], bfv[4];                                                           \
    _Pragma("unroll") for (int i = 0; i < 4; i++)                                \
      af[i] = *(const s8v*)(Ar[i] + k0);                                         \
    _Pragma("unroll") for (int j = 0; j < 4; j++)                                \
      bfv[j] = *(const s8v*)(Br[j] + k0);                                        \
    _Pragma("unroll") for (int i = 0; i < 4; i++)                                \
      _Pragma("unroll") for (int j = 0; j < 4; j++)                              \
        acc[i][j] = __builtin_amdgcn_mfma_f32_16x16x32_bf16(af[i], bfv[j],       \
                                                            acc[i][j], 0, 0, 0); \
  }

// ---------------- fused QKV GEMM; z=0 -> Q (pre-scaled), z=1 -> K, z=2 -> V transposed ----------------
__global__ __launch_bounds__(256, 2) void gemm_qkv(const u16* __restrict__ A, const u16* __restrict__ Wt,
                                                   u16* __restrict__ Qb, u16* __restrict__ Kb,
                                                   u16* __restrict__ Vtg) {
  const int z = blockIdx.z;
  const u16* Bt = Wt + (size_t)z * DIM * DIM;
  GEMM_SETUP_AND_LOOP()
  if (z == 2) {
    // write V transposed: Vtg[((b*NH+h)*HD+d)*SEQ + s]
    #pragma unroll
    for (int i = 0; i < 4; i++) {
      #pragma unroll
      for (int j = 0; j < 4; j++) {
        int gm0 = m0 + waveM * 64 + i * 16 + quad * 4;
        int gn = n0 + waveN * 64 + j * 16 + l16;
        int b = gm0 >> 11, s0 = gm0 & (SEQ - 1), hh = gn >> 6, d = gn & (HD - 1);
        u16x4 o;
        #pragma unroll
        for (int r = 0; r < 4; r++) o[r] = f2bf(acc[i][j][r]);
        *(u16x4*)(Vtg + ((size_t)(b * NH + hh) * HD + d) * SEQ + s0) = o;
      }
    }
  } else {
    u16* C = (z == 0) ? Qb : Kb;
    #pragma unroll
    for (int i = 0; i < 4; i++) {
      #pragma unroll
      for (int j = 0; j < 4; j++) {
        int gn = n0 + waveN * 64 + j * 16 + l16;
        #pragma unroll
        for (int r = 0; r < 4; r++) {
          int gm = m0 + waveM * 64 + i * 16 + quad * 4 + r;
          C[(size_t)gm * DIM + gn] = f2bf(acc[i][j][r]);
        }
      }
    }
  }
}

// ---------------- projection GEMM: out = ctx * Wo^T + bias (fp32 out) ----------------
__global__ __launch_bounds__(256, 2) void gemm_proj(const u16* __restrict__ A, const u16* __restrict__ Bt,
                                                    float* __restrict__ Cf, const float* __restrict__ bias) {
  GEMM_SETUP_AND_LOOP()
  #pragma unroll
  for (int i = 0; i < 4; i++) {
    #pragma unroll
    for (int j = 0; j < 4; j++) {
      int gn = n0 + waveN * 64 + j * 16 + l16;
      float bv = bias[gn];
      #pragma unroll
      for (int r = 0; r < 4; r++) {
        int gm = m0 + waveM * 64 + i * 16 + quad * 4 + r;
        Cf[(size_t)gm * DIM + gn] = acc[i][j][r] + bv;
      }
    }
  }
}

// ---------------- MFMA flash attention (causal), all-direct loads, barrier-free K-loop ----------------
// S^T = K*Q^T with the K row-permutation pi folded into the load address:
// A-operand lane l16 of tile mi reads global kv row kv0 + rowoff(mi,l16),
// rowoff = (mi&1)*32 + (mi>>1)*4 + (l16>>2)*8 + (l16&3)  [inverse of r3's krow map].
// P^T registers are directly the PV B-fragment. O^T = Vt*P^T in C-layout.
// Each wave loops only to its own causal bound (no barriers -> no balance cost).
__global__ __launch_bounds__(256, 2) void flash_attn_mfma(const u16* __restrict__ Qb,
                                                          const u16* __restrict__ Kb,
                                                          const u16* __restrict__ Vtg,
                                                          u16* __restrict__ Ob) {
  const int h = blockIdx.x, px = blockIdx.y, bb = blockIdx.z;
  const int t = threadIdx.x;
  const int lane = t & 63, w = t >> 6;
  const int quad = lane >> 4, l16 = lane & 15;

  __shared__ u16 QPs[QT * PAD];  // epilogue transpose bounce only

  const size_t qkbase = (size_t)bb * SEQ * DIM + h * HD;
  const size_t vbase = ((size_t)bb * NH + h) * (size_t)HD * SEQ;

  // K fragment row pointers (permutation baked in)
  const u16* Kp[4];
  #pragma unroll
  for (int mi = 0; mi < 4; mi++) {
    const int rowoff = (mi & 1) * 32 + (mi >> 1) * 4 + (l16 >> 2) * 8 + (l16 & 3);
    Kp[mi] = Kb + qkbase + (size_t)rowoff * DIM + quad * 8;
  }
  // V fragment row pointers: row = d (di*16 + l16), col = kv
  const u16* Vp[4];
  #pragma unroll
  for (int di = 0; di < 4; di++)
    Vp[di] = Vtg + vbase + (size_t)(di * 16 + l16) * SEQ + quad * 8;

  for (int pass = 0; pass < 2; pass++) {
    const int qi = (pass == 0) ? px : (SEQ / QT - 1 - px);
    const int q0 = qi * QT;
    const int wq = q0 + w * 32;
    const int itmax = (wq + 31) >> 6;  // last tile with any unmasked kv for this wave

    // Q B-fragments, direct (Q pre-scaled by 0.125*log2e via Wq)
    s8v qf[2][2];
    #pragma unroll
    for (int ni = 0; ni < 2; ni++)
      #pragma unroll
      for (int kc = 0; kc < 2; kc++)
        qf[ni][kc] = *(const s8v*)(Qb + qkbase +
            (size_t)(q0 + w * 32 + ni * 16 + l16) * DIM + kc * 32 + quad * 8);

    float mrun[2] = {-1e30f, -1e30f}, lrun[2] = {0.f, 0.f};
    v4f O[4][2];
    #pragma unroll
    for (int di = 0; di < 4; di++)
      #pragma unroll
      for (int ni = 0; ni < 2; ni++) O[di][ni] = (v4f){0.f, 0.f, 0.f, 0.f};

    for (int it = 0; it <= itmax; ++it) {
      const int kv0 = it * KT;

      // ---- direct fragment loads (pipelined by HW scoreboard) ----
      s8v kf[4][2], vf[4][2];
      #pragma unroll
      for (int mi = 0; mi < 4; mi++) {
        kf[mi][0] = *(const s8v*)(Kp[mi] + (size_t)kv0 * DIM);
        kf[mi][1] = *(const s8v*)(Kp[mi] + (size_t)kv0 * DIM + 32);
      }
      #pragma unroll
      for (int di = 0; di < 4; di++) {
        vf[di][0] = *(const s8v*)(Vp[di] + kv0);
        vf[di][1] = *(const s8v*)(Vp[di] + kv0 + 32);
      }

      // ---- S^T = K*Q^T : sc[mi][ni], rows kv (permuted), cols q ----
      v4f sc[4][2];
      #pragma unroll
      for (int mi = 0; mi < 4; mi++)
        #pragma unroll
        for (int ni = 0; ni < 2; ni++) sc[mi][ni] = (v4f){0.f, 0.f, 0.f, 0.f};
      #pragma unroll
      for (int kc = 0; kc < 2; kc++)
        #pragma unroll
        for (int mi = 0; mi < 4; mi++) {
          sc[mi][0] = __builtin_amdgcn_mfma_f32_16x16x32_bf16(kf[mi][kc], qf[0][kc], sc[mi][0], 0, 0, 0);
          sc[mi][1] = __builtin_amdgcn_mfma_f32_16x16x32_bf16(kf[mi][kc], qf[1][kc], sc[mi][1], 0, 0, 0);
        }

      // ---- causal mask: kv_g = kv0 + (mi&1)*32 + quad*8 + (mi>>1)*4 + r ----
      if (kv0 + KT > wq) {
        #pragma unroll
        for (int mi = 0; mi < 4; mi++) {
          const int kvb = kv0 + (mi & 1) * 32 + quad * 8 + (mi >> 1) * 4;
          #pragma unroll
          for (int ni = 0; ni < 2; ni++) {
            const int qg = wq + ni * 16 + l16;
            #pragma unroll
            for (int r = 0; r < 4; r++)
              if (kvb + r > qg) sc[mi][ni][r] = -1e30f;
          }
        }
      }

      // ---- online softmax: 16 in-register kv values + 2 shuffles per reduce ----
      float alpha[2];
      #pragma unroll
      for (int ni = 0; ni < 2; ni++) {
        float mx = -1e30f;
        #pragma unroll
        for (int mi = 0; mi < 4; mi++)
          #pragma unroll
          for (int r = 0; r < 4; r++) mx = fmaxf(mx, sc[mi][ni][r]);
        mx = fmaxf(mx, __shfl_xor(mx, 16, 64));
        mx = fmaxf(mx, __shfl_xor(mx, 32, 64));
        const float mnew = fmaxf(mrun[ni], mx);
        alpha[ni] = fast_exp2(mrun[ni] - mnew);
        mrun[ni] = mnew;
        float rsum = 0.f;
        #pragma unroll
        for (int mi = 0; mi < 4; mi++)
          #pragma unroll
          for (int r = 0; r < 4; r++) {
            float p = fast_exp2(sc[mi][ni][r] - mnew);
            sc[mi][ni][r] = p;
            rsum += p;
          }
        rsum += __shfl_xor(rsum, 16, 64);
        rsum += __shfl_xor(rsum, 32, 64);
        lrun[ni] = lrun[ni] * alpha[ni] + rsum;
      }
      // skip the 32-mul rescale when no lane's max moved (alpha == 1 exactly)
      if (__any((alpha[0] != 1.0f) | (alpha[1] != 1.0f))) {
        #pragma unroll
        for (int di = 0; di < 4; di++)
          #pragma unroll
          for (int ni = 0; ni < 2; ni++)
            #pragma unroll
            for (int r = 0; r < 4; r++) O[di][ni][r] *= alpha[ni];
      }

      // ---- pack P^T as PV B-frag via v_perm (trunc bf16): shorts j = P[q][kc*32+quad*8+j] ----
      s8v pf[2][2];
      #pragma unroll
      for (int ni = 0; ni < 2; ni++)
        #pragma unroll
        for (int kc = 0; kc < 2; kc++) {
          u32x4 pw;
          pw[0] = pk2(sc[kc][ni][1], sc[kc][ni][0]);
          pw[1] = pk2(sc[kc][ni][3], sc[kc][ni][2]);
          pw[2] = pk2(sc[kc + 2][ni][1], sc[kc + 2][ni][0]);
          pw[3] = pk2(sc[kc + 2][ni][3], sc[kc + 2][ni][2]);
          pf[ni][kc] = __builtin_bit_cast(s8v, pw);
        }

      // ---- PV: O^T[d][q] += Vt * P^T ----
      #pragma unroll
      for (int kc = 0; kc < 2; kc++)
        #pragma unroll
        for (int di = 0; di < 4; di++) {
          O[di][0] = __builtin_amdgcn_mfma_f32_16x16x32_bf16(vf[di][kc], pf[0][kc], O[di][0], 0, 0, 0);
          O[di][1] = __builtin_amdgcn_mfma_f32_16x16x32_bf16(vf[di][kc], pf[1][kc], O[di][1], 0, 0, 0);
        }
    }

    // ---- epilogue: normalize, transpose via LDS (wave-private rows), coalesced write ----
    const float inv0 = 1.f / lrun[0], inv1 = 1.f / lrun[1];
    #pragma unroll
    for (int di = 0; di < 4; di++)
      #pragma unroll
      for (int ni = 0; ni < 2; ni++) {
        const float inv = ni ? inv1 : inv0;
        #pragma unroll
        for (int r = 0; r < 4; r++)
          QPs[(w * 32 + ni * 16 + l16) * PAD + di * 16 + quad * 4 + r] = f2bf(O[di][ni][r] * inv);
      }
    __syncthreads();
    {
      const int r = t >> 1, c0 = (t & 1) * 32;
      u16* dst = Ob + qkbase + (size_t)(q0 + r) * DIM + c0;
      #pragma unroll
      for (int ch = 0; ch < 4; ch++)
        *(u16x8*)(dst + ch * 8) = *(const u16x8*)(QPs + r * PAD + c0 + ch * 8);
    }
    __syncthreads();  // QPs free before next pass's writes
  }
}

// ---------------- launch ----------------
extern "C" void kernel_launch(void* const* d_in, const int* in_sizes, int n_in,
                              void* d_out, int out_size, void* d_ws, size_t ws_size,
                              hipStream_t stream) {
  (void)in_sizes; (void)n_in; (void)out_size; (void)ws_size;
  const float* x  = (const float*)d_in[0];
  const float* Wq = (const float*)d_in[1];
  const float* Wk = (const float*)d_in[2];
  const float* Wv = (const float*)d_in[3];
  const float* Wo = (const float*)d_in[4];
  const float* bo = (const float*)d_in[5];
  float* out = (float*)d_out;

  char* ws = (char*)d_ws;
  const size_t MB = 1024ull * 1024ull;
  u16* Xb  = (u16*)(ws);             // 16 MB: x bf16 [8192][1024]
  u16* Wt  = (u16*)(ws + 16 * MB);   //  8 MB: Wq(scaled),Wk,Wv,Wo transposed bf16
  u16* Qb  = (u16*)(ws + 24 * MB);   // 16 MB
  u16* Kb  = (u16*)(ws + 40 * MB);   // 16 MB
  u16* Vtg = (u16*)(ws + 56 * MB);   // 16 MB: V transposed [b][h][d][s]
  u16* Cb  = (u16*)(ws + 72 * MB);   // 16 MB: ctx -> 88 MB total

  const int NTOK = BSZ * SEQ;  // 8192
  const int n4 = NTOK * DIM / 4;
  cast_bf16_kernel<<<(n4 + 255) / 256, 256, 0, stream>>>(x, Xb, n4);
  transpose_cast_kernel<<<dim3(32, 32, 4), 256, 0, stream>>>(Wq, Wk, Wv, Wo, Wt);

  gemm_qkv<<<dim3(DIM / 128, NTOK / 128, 3), 256, 0, stream>>>(Xb, Wt, Qb, Kb, Vtg);

  flash_attn_mfma<<<dim3(NH, SEQ / QT / 2, BSZ), 256, 0, stream>>>(Qb, Kb, Vtg, Cb);

  gemm_proj<<<dim3(DIM / 128, NTOK / 128), 256, 0, stream>>>(Cb, Wt + 3ull * DIM * DIM, out, bo);
}

// Round 7
// 404.536 us; speedup vs baseline: 1.1475x; 1.1475x over previous
//
#include <hip/hip_runtime.h>

// ---- problem constants ----
#define BSZ 4
#define SEQ 2048
#define DIM 1024
#define NH  16
#define HD  64
#define QT  128   // q rows per block pass (flash)
#define KT  64    // kv rows per tile (flash)
#define PAD 72    // u16 row stride in flash LDS

typedef float v4f __attribute__((ext_vector_type(4)));
typedef short s8v __attribute__((ext_vector_type(8)));
typedef unsigned short u16;
typedef unsigned short u16x8 __attribute__((ext_vector_type(8)));
typedef unsigned short u16x4 __attribute__((ext_vector_type(4)));
typedef unsigned int u32;

__device__ __forceinline__ u16 f2bf(float f) {
  u32 u = __builtin_bit_cast(u32, f);
  u32 r = u + 0x7fffu + ((u >> 16) & 1u);  // RNE
  return (u16)(r >> 16);
}
__device__ __forceinline__ float bf2f(u16 h) {
  return __builtin_bit_cast(float, (u32)h << 16);
}
__device__ __forceinline__ float fast_exp2(float x) {
#if __has_builtin(__builtin_amdgcn_exp2f)
  return __builtin_amdgcn_exp2f(x);
#else
  return exp2f(x);
#endif
}
// async global->LDS, 16B per lane; lds ptr must be wave-uniform (HW adds lane*16)
__device__ __forceinline__ void gll16(const u16* g, u16* l) {
  __builtin_amdgcn_global_load_lds((const __attribute__((address_space(1))) void*)g,
                                   (__attribute__((address_space(3))) void*)l, 16, 0, 0);
}
// s_waitcnt imm: vmcnt[3:0] | expcnt<<4 | lgkmcnt<<8 | vmcnt[5:4]<<14
#define WAITCNT_VM8 0xF78  // vmcnt(8), lgkm/exp unconstrained
#define WAITCNT_VM0 0xF70  // vmcnt(0)

// ---------------- cast x (fp32) -> bf16 ----------------
__global__ __launch_bounds__(256) void cast_bf16_kernel(const float* __restrict__ x,
                                                        u16* __restrict__ o, int n4) {
  int i = blockIdx.x * 256 + threadIdx.x;
  if (i >= n4) return;
  v4f v = reinterpret_cast<const v4f*>(x)[i];
  u16x4 r;
  #pragma unroll
  for (int c = 0; c < 4; c++) r[c] = f2bf(v[c]);
  reinterpret_cast<u16x4*>(o)[i] = r;
}

// ---------------- transpose + cast W[k][n] -> Wt[n][k] bf16 ----------------
// z==0 (Wq) folds in the attention scale 1/sqrt(HD)*log2(e): Q leaves the QKV
// GEMM pre-scaled for the exp2-domain softmax (flash staging is a pure copy).
__global__ __launch_bounds__(256) void transpose_cast_kernel(const float* __restrict__ W0,
                                                             const float* __restrict__ W1,
                                                             const float* __restrict__ W2,
                                                             const float* __restrict__ W3,
                                                             u16* __restrict__ out) {
  const float* W = blockIdx.z == 0 ? W0 : blockIdx.z == 1 ? W1 : blockIdx.z == 2 ? W2 : W3;
  const float scale = (blockIdx.z == 0) ? 0.18033688011112042f : 1.0f;
  u16* T = out + (size_t)blockIdx.z * DIM * DIM;
  __shared__ float tile[32][33];
  int tx = threadIdx.x & 31, ty = threadIdx.x >> 5;
  int bn = blockIdx.x * 32, bk = blockIdx.y * 32;
  #pragma unroll
  for (int r = 0; r < 4; r++) {
    int k = bk + ty + r * 8;
    tile[ty + r * 8][tx] = W[(size_t)k * DIM + bn + tx];
  }
  __syncthreads();
  #pragma unroll
  for (int r = 0; r < 4; r++) {
    int n = bn + ty + r * 8;
    T[(size_t)n * DIM + bk + tx] = f2bf(tile[tx][ty + r * 8] * scale);
  }
}

// ======== wave-private barrier-free GEMM core (128x128 block, 64x64 per wave) ========
// Each wave stages its OWN 64-row A-slice and 64-row B-slice (BK=32) via
// global_load_lds into wave-private LDS double buffers -> NO __syncthreads in
// the K-loop, no workgroup vmcnt(0) drain. Explicit s_waitcnt vmcnt(8) after
// issuing the next half's 8 prefetch loads drains only the CURRENT half's 8
// loads; the prefetch stays in flight across the MFMA phase (AITER-style).
// WAR on the overwritten buffer is safe: the compiler's lgkmcnt waits before
// the previous half's MFMAs guarantee its ds_reads completed.
// LDS per wave-buffer (16B chunks): chunk = i*64 + kk*16 + (m&15) -> gll16
// destination contiguous in lane order. XCD swizzle: flat = x + 8y; xcd =
// flat&7 owns an 8-panel M-slab x all N (per-XCD L2 ~ 2MB A-slab + 2MB W).

#define GEMM_HALF(rdofs, wrofs, knext)                                            \
  { if ((knext) < DIM) {                                                          \
      _Pragma("unroll") for (int i = 0; i < 4; i++)                               \
        gll16(Ag[i] + (knext), Aw + (wrofs) + i * 512);                           \
      _Pragma("unroll") for (int j = 0; j < 4; j++)                               \
        gll16(Bg[j] + (knext), Bw + (wrofs) + j * 512);                           \
      __builtin_amdgcn_s_waitcnt(WAITCNT_VM8);                                    \
    } else {                                                                      \
      __builtin_amdgcn_s_waitcnt(WAITCNT_VM0);                                    \
    }                                                                             \
    s8v af[4], bfv[4];                                                            \
    _Pragma("unroll") for (int i = 0; i < 4; i++)                                 \
      af[i] = *(const s8v*)(Aw + (rdofs) + i * 512 + quad * 128 + l16 * 8);       \
    _Pragma("unroll") for (int j = 0; j < 4; j++)                                 \
      bfv[j] = *(const s8v*)(Bw + (rdofs) + j * 512 + quad * 128 + l16 * 8);      \
    _Pragma("unroll") for (int i = 0; i < 4; i++)                                 \
      _Pragma("unroll") for (int j = 0; j < 4; j++)                               \
        acc[i][j] = __builtin_amdgcn_mfma_f32_16x16x32_bf16(af[i], bfv[j],        \
                                                            acc[i][j], 0, 0, 0); }

#define GEMM_SETUP_AND_LOOP()                                                     \
  const int flat = blockIdx.x + 8 * blockIdx.y;                                   \
  const int xcd = flat & 7, slot = flat >> 3;                                     \
  const int m0 = (xcd * 8 + (slot & 7)) * 128;                                    \
  const int n0 = (slot >> 3) * 128;                                               \
  const int t = threadIdx.x;                                                      \
  const int lane = t & 63, w = t >> 6;                                            \
  const int waveM = w >> 1, waveN = w & 1;                                        \
  const int quad = lane >> 4, l16 = lane & 15;                                    \
  __shared__ u16 Al[16384];                                                       \
  __shared__ u16 Bl[16384];                                                       \
  u16* Aw = Al + w * 4096;                                                        \
  u16* Bw = Bl + w * 4096;                                                        \
  v4f acc[4][4];                                                                  \
  _Pragma("unroll") for (int i = 0; i < 4; i++)                                   \
    _Pragma("unroll") for (int j = 0; j < 4; j++)                                 \
      acc[i][j] = (v4f){0.f, 0.f, 0.f, 0.f};                                      \
  const int sR = lane & 15, sC = lane >> 4;                                       \
  const u16* Ag[4];                                                               \
  const u16* Bg[4];                                                               \
  _Pragma("unroll") for (int i = 0; i < 4; i++)                                   \
    Ag[i] = A + (size_t)(m0 + waveM * 64 + i * 16 + sR) * DIM + sC * 8;           \
  _Pragma("unroll") for (int j = 0; j < 4; j++)                                   \
    Bg[j] = Bt + (size_t)(n0 + waveN * 64 + j * 16 + sR) * DIM + sC * 8;          \
  _Pragma("unroll") for (int i = 0; i < 4; i++) gll16(Ag[i], Aw + i * 512);       \
  _Pragma("unroll") for (int j = 0; j < 4; j++) gll16(Bg[j], Bw + j * 512);       \
  for (int k0 = 0; k0 < DIM; k0 += 64) {                                          \
    GEMM_HALF(0, 2048, k0 + 32)                                                   \
    GEMM_HALF(2048, 0, k0 + 64)                                                   \
  }

// ---------------- fused QKV GEMM; z=0 -> Q (pre-scaled), z=1 -> K, z=2 -> V transposed ----------------
__global__ __launch_bounds__(256, 2) void gemm_qkv(const u16* __restrict__ A, const u16* __restrict__ Wt,
                                                   u16* __restrict__ Qb, u16* __restrict__ Kb,
                                                   u16* __restrict__ Vtg) {
  const int z = blockIdx.z;
  const u16* Bt = Wt + (size_t)z * DIM * DIM;
  GEMM_SETUP_AND_LOOP()
  if (z == 2) {
    // write V transposed: Vtg[((b*NH+h)*HD+d)*SEQ + s]
    #pragma unroll
    for (int i = 0; i < 4; i++) {
      #pragma unroll
      for (int j = 0; j < 4; j++) {
        int gm0 = m0 + waveM * 64 + i * 16 + quad * 4;
        int gn = n0 + waveN * 64 + j * 16 + l16;
        int b = gm0 >> 11, s0 = gm0 & (SEQ - 1), hh = gn >> 6, d = gn & (HD - 1);
        u16x4 o;
        #pragma unroll
        for (int r = 0; r < 4; r++) o[r] = f2bf(acc[i][j][r]);
        *(u16x4*)(Vtg + ((size_t)(b * NH + hh) * HD + d) * SEQ + s0) = o;
      }
    }
  } else {
    u16* C = (z == 0) ? Qb : Kb;
    #pragma unroll
    for (int i = 0; i < 4; i++) {
      #pragma unroll
      for (int j = 0; j < 4; j++) {
        int gn = n0 + waveN * 64 + j * 16 + l16;
        #pragma unroll
        for (int r = 0; r < 4; r++) {
          int gm = m0 + waveM * 64 + i * 16 + quad * 4 + r;
          C[(size_t)gm * DIM + gn] = f2bf(acc[i][j][r]);
        }
      }
    }
  }
}

// ---------------- projection GEMM: out = ctx * Wo^T + bias (fp32 out) ----------------
__global__ __launch_bounds__(256, 2) void gemm_proj(const u16* __restrict__ A, const u16* __restrict__ Bt,
                                                    float* __restrict__ Cf, const float* __restrict__ bias) {
  GEMM_SETUP_AND_LOOP()
  #pragma unroll
  for (int i = 0; i < 4; i++) {
    #pragma unroll
    for (int j = 0; j < 4; j++) {
      int gn = n0 + waveN * 64 + j * 16 + l16;
      float bv = bias[gn];
      #pragma unroll
      for (int r = 0; r < 4; r++) {
        int gm = m0 + waveM * 64 + i * 16 + quad * 4 + r;
        Cf[(size_t)gm * DIM + gn] = acc[i][j][r] + bv;
      }
    }
  }
}

// ---------------- MFMA flash attention (causal), transposed scores (R4 known-good) ----------------
// S^T = K*Q^T (K rows permuted so P^T registers are directly the PV B-fragment).
// Softmax over kv: 16 in-register values + 2 shfl_xor. O^T = Vt*P^T in C-layout.
// Causal balance: block pair {px, 15-px} -> 34 KV-tiles each. Grid (NH, px, BSZ).
__global__ __launch_bounds__(256, 3) void flash_attn_mfma(const u16* __restrict__ Qb,
                                                          const u16* __restrict__ Kb,
                                                          const u16* __restrict__ Vtg,
                                                          u16* __restrict__ Ob) {
  const int h = blockIdx.x, px = blockIdx.y, bb = blockIdx.z;
  const int t = threadIdx.x;
  const int lane = t & 63, w = t >> 6;
  const int quad = lane >> 4, l16 = lane & 15;

  __shared__ u16 QPs[QT * PAD];  // Q staging, then O^T epilogue bounce
  __shared__ u16 Ks[KT * PAD];   // K tile, rows permuted by pi^-1
  __shared__ u16 Vs[HD * PAD];   // V tile, [d][kv]

  const size_t qkbase = (size_t)bb * SEQ * DIM + h * HD;
  const size_t vbase = ((size_t)bb * NH + h) * (size_t)HD * SEQ;

  const int vrow = t >> 2, scol = (t & 3) * 16;
  const int krow = ((vrow >> 5) + 2 * ((vrow >> 2) & 1)) * 16 + ((vrow >> 3) & 3) * 4 + (vrow & 3);

  for (int pass = 0; pass < 2; pass++) {
    const int qi = (pass == 0) ? px : (SEQ / QT - 1 - px);
    const int q0 = qi * QT;
    const int wq = q0 + w * 32;
    const int ntiles = 2 * qi + 2;

    __syncthreads();  // QPs free (previous pass epilogue complete)

    // stage Q (pure copy; scale folded into Wq)
    {
      const int r = t >> 1, c0 = (t & 1) * 32;
      const u16* src = Qb + qkbase + (size_t)(q0 + r) * DIM + c0;
      #pragma unroll
      for (int ch = 0; ch < 4; ch++)
        *(u16x8*)(QPs + r * PAD + c0 + ch * 8) = *(const u16x8*)(src + ch * 8);
    }
    __syncthreads();

    // Q B-fragments: B[n=q][k=d]
    s8v qf[2][2];
    #pragma unroll
    for (int ni = 0; ni < 2; ni++)
      #pragma unroll
      for (int kc = 0; kc < 2; kc++)
        qf[ni][kc] = *(const s8v*)(QPs + (w * 32 + ni * 16 + l16) * PAD + kc * 32 + quad * 8);

    // preload KV tile 0 into registers
    u16x8 kr0, kr1, vr0, vr1;
    {
      const u16* kp = Kb + qkbase + (size_t)vrow * DIM + scol;
      kr0 = *(const u16x8*)kp; kr1 = *(const u16x8*)(kp + 8);
      const u16* vp = Vtg + vbase + (size_t)vrow * SEQ + scol;
      vr0 = *(const u16x8*)vp; vr1 = *(const u16x8*)(vp + 8);
    }

    float mrun[2] = {-1e30f, -1e30f}, lrun[2] = {0.f, 0.f};
    v4f O[4][2];
    #pragma unroll
    for (int di = 0; di < 4; di++)
      #pragma unroll
      for (int ni = 0; ni < 2; ni++) O[di][ni] = (v4f){0.f, 0.f, 0.f, 0.f};

    for (int it = 0; it < ntiles; ++it) {
      const int kv0 = it * KT;
      __syncthreads();
      *(u16x8*)(Ks + krow * PAD + scol) = kr0;
      *(u16x8*)(Ks + krow * PAD + scol + 8) = kr1;
      *(u16x8*)(Vs + vrow * PAD + scol) = vr0;
      *(u16x8*)(Vs + vrow * PAD + scol + 8) = vr1;
      __syncthreads();
      if (it + 1 < ntiles) {  // prefetch next tile (consumed after next barrier)
        const int nkv = kv0 + KT;
        const u16* kp = Kb + qkbase + (size_t)(nkv + vrow) * DIM + scol;
        kr0 = *(const u16x8*)kp; kr1 = *(const u16x8*)(kp + 8);
        const u16* vp = Vtg + vbase + (size_t)vrow * SEQ + nkv + scol;
        vr0 = *(const u16x8*)vp; vr1 = *(const u16x8*)(vp + 8);
      }
      if (kv0 > wq + 31) continue;  // tile fully masked for this wave

      // ---- S^T = K*Q^T : sc[mi][ni], rows kv (permuted), cols q ----
      v4f sc[4][2];
      #pragma unroll
      for (int mi = 0; mi < 4; mi++)
        #pragma unroll
        for (int ni = 0; ni < 2; ni++) sc[mi][ni] = (v4f){0.f, 0.f, 0.f, 0.f};
      #pragma unroll
      for (int kc = 0; kc < 2; kc++) {
        #pragma unroll
        for (int mi = 0; mi < 4; mi++) {
          s8v kf = *(const s8v*)(Ks + (mi * 16 + l16) * PAD + kc * 32 + quad * 8);
          sc[mi][0] = __builtin_amdgcn_mfma_f32_16x16x32_bf16(kf, qf[0][kc], sc[mi][0], 0, 0, 0);
          sc[mi][1] = __builtin_amdgcn_mfma_f32_16x16x32_bf16(kf, qf[1][kc], sc[mi][1], 0, 0, 0);
        }
      }

      // ---- causal mask: kv_g = kv0 + (mi&1)*32 + quad*8 + (mi>>1)*4 + r ----
      if (kv0 + KT > wq) {
        #pragma unroll
        for (int mi = 0; mi < 4; mi++) {
          const int kvb = kv0 + (mi & 1) * 32 + quad * 8 + (mi >> 1) * 4;
          #pragma unroll
          for (int ni = 0; ni < 2; ni++) {
            const int qg = wq + ni * 16 + l16;
            #pragma unroll
            for (int r = 0; r < 4; r++)
              if (kvb + r > qg) sc[mi][ni][r] = -1e30f;
          }
        }
      }

      // ---- online softmax: per lane 16 kv values, 2 shuffles per reduce ----
      float alpha[2];
      #pragma unroll
      for (int ni = 0; ni < 2; ni++) {
        float mx = -1e30f;
        #pragma unroll
        for (int mi = 0; mi < 4; mi++)
          #pragma unroll
          for (int r = 0; r < 4; r++) mx = fmaxf(mx, sc[mi][ni][r]);
        mx = fmaxf(mx, __shfl_xor(mx, 16, 64));
        mx = fmaxf(mx, __shfl_xor(mx, 32, 64));
        const float mnew = fmaxf(mrun[ni], mx);
        alpha[ni] = fast_exp2(mrun[ni] - mnew);
        mrun[ni] = mnew;
        float rsum = 0.f;
        #pragma unroll
        for (int mi = 0; mi < 4; mi++)
          #pragma unroll
          for (int r = 0; r < 4; r++) {
            float p = fast_exp2(sc[mi][ni][r] - mnew);
            sc[mi][ni][r] = p;
            rsum += p;
          }
        rsum += __shfl_xor(rsum, 16, 64);
        rsum += __shfl_xor(rsum, 32, 64);
        lrun[ni] = lrun[ni] * alpha[ni] + rsum;
      }
      #pragma unroll
      for (int di = 0; di < 4; di++)
        #pragma unroll
        for (int ni = 0; ni < 2; ni++)
          #pragma unroll
          for (int r = 0; r < 4; r++) O[di][ni][r] *= alpha[ni];

      // ---- pack P^T as PV B-frag: pf[ni][kc][j] = P[q][kv=kc*32+quad*8+j] ----
      s8v pf[2][2];
      #pragma unroll
      for (int ni = 0; ni < 2; ni++)
        #pragma unroll
        for (int kc = 0; kc < 2; kc++)
          #pragma unroll
          for (int j = 0; j < 8; j++)
            pf[ni][kc][j] = (short)f2bf(sc[kc + 2 * (j >> 2)][ni][j & 3]);

      // ---- PV: O^T[d][q] += Vt * P^T ----
      #pragma unroll
      for (int kc = 0; kc < 2; kc++) {
        #pragma unroll
        for (int di = 0; di < 4; di++) {
          s8v vf = *(const s8v*)(Vs + (di * 16 + l16) * PAD + kc * 32 + quad * 8);
          O[di][0] = __builtin_amdgcn_mfma_f32_16x16x32_bf16(vf, pf[0][kc], O[di][0], 0, 0, 0);
          O[di][1] = __builtin_amdgcn_mfma_f32_16x16x32_bf16(vf, pf[1][kc], O[di][1], 0, 0, 0);
        }
      }
    }

    // ---- epilogue: normalize, transpose via LDS (wave-private rows), coalesced write ----
    const float inv0 = 1.f / lrun[0], inv1 = 1.f / lrun[1];
    #pragma unroll
    for (int di = 0; di < 4; di++)
      #pragma unroll
      for (int ni = 0; ni < 2; ni++) {
        const float inv = ni ? inv1 : inv0;
        #pragma unroll
        for (int r = 0; r < 4; r++)
          QPs[(w * 32 + ni * 16 + l16) * PAD + di * 16 + quad * 4 + r] = f2bf(O[di][ni][r] * inv);
      }
    __syncthreads();
    {
      const int r = t >> 1, c0 = (t & 1) * 32;
      u16* dst = Ob + qkbase + (size_t)(q0 + r) * DIM + c0;
      #pragma unroll
      for (int ch = 0; ch < 4; ch++)
        *(u16x8*)(dst + ch * 8) = *(const u16x8*)(QPs + r * PAD + c0 + ch * 8);
    }
  }
}

// ---------------- launch ----------------
extern "C" void kernel_launch(void* const* d_in, const int* in_sizes, int n_in,
                              void* d_out, int out_size, void* d_ws, size_t ws_size,
                              hipStream_t stream) {
  (void)in_sizes; (void)n_in; (void)out_size; (void)ws_size;
  const float* x  = (const float*)d_in[0];
  const float* Wq = (const float*)d_in[1];
  const float* Wk = (const float*)d_in[2];
  const float* Wv = (const float*)d_in[3];
  const float* Wo = (const float*)d_in[4];
  const float* bo = (const float*)d_in[5];
  float* out = (float*)d_out;

  char* ws = (char*)d_ws;
  const size_t MB = 1024ull * 1024ull;
  u16* Xb  = (u16*)(ws);             // 16 MB: x bf16 [8192][1024]
  u16* Wt  = (u16*)(ws + 16 * MB);   //  8 MB: Wq(scaled),Wk,Wv,Wo transposed bf16
  u16* Qb  = (u16*)(ws + 24 * MB);   // 16 MB
  u16* Kb  = (u16*)(ws + 40 * MB);   // 16 MB
  u16* Vtg = (u16*)(ws + 56 * MB);   // 16 MB: V transposed [b][h][d][s]
  u16* Cb  = (u16*)(ws + 72 * MB);   // 16 MB: ctx -> 88 MB total

  const int NTOK = BSZ * SEQ;  // 8192
  const int n4 = NTOK * DIM / 4;
  cast_bf16_kernel<<<(n4 + 255) / 256, 256, 0, stream>>>(x, Xb, n4);
  transpose_cast_kernel<<<dim3(32, 32, 4), 256, 0, stream>>>(Wq, Wk, Wv, Wo, Wt);

  gemm_qkv<<<dim3(DIM / 128, NTOK / 128, 3), 256, 0, stream>>>(Xb, Wt, Qb, Kb, Vtg);

  flash_attn_mfma<<<dim3(NH, SEQ / QT / 2, BSZ), 256, 0, stream>>>(Qb, Kb, Vtg, Cb);

  gemm_proj<<<dim3(DIM / 128, NTOK / 128), 256, 0, stream>>>(Cb, Wt + 3ull * DIM * DIM, out, bo);
}

// Round 8
// 303.240 us; speedup vs baseline: 1.5308x; 1.3340x over previous
//
#include <hip/hip_runtime.h>

// ---- problem constants ----
#define BSZ 4
#define SEQ 2048
#define DIM 1024
#define NH  16
#define HD  64
#define QT  128   // q rows per block pass (flash)
#define KT  64    // kv rows per tile (flash)
#define PAD 72    // u16 row stride in flash LDS

typedef float v4f __attribute__((ext_vector_type(4)));
typedef short s8v __attribute__((ext_vector_type(8)));
typedef unsigned short u16;
typedef unsigned short u16x8 __attribute__((ext_vector_type(8)));
typedef unsigned short u16x4 __attribute__((ext_vector_type(4)));
typedef unsigned int u32;

__device__ __forceinline__ u16 f2bf(float f) {
  u32 u = __builtin_bit_cast(u32, f);
  u32 r = u + 0x7fffu + ((u >> 16) & 1u);  // RNE
  return (u16)(r >> 16);
}
__device__ __forceinline__ float bf2f(u16 h) {
  return __builtin_bit_cast(float, (u32)h << 16);
}
__device__ __forceinline__ float fast_exp2(float x) {
#if __has_builtin(__builtin_amdgcn_exp2f)
  return __builtin_amdgcn_exp2f(x);
#else
  return exp2f(x);
#endif
}
// async global->LDS, 16B per lane; lds ptr must be wave-uniform (HW adds lane*16)
__device__ __forceinline__ void gll16(const u16* g, u16* l) {
  __builtin_amdgcn_global_load_lds((const __attribute__((address_space(1))) void*)g,
                                   (__attribute__((address_space(3))) void*)l, 16, 0, 0);
}
// raw s_barrier via inline asm: SIInsertWaitcnts does NOT recognize it, so no
// forced vmcnt(0) drain (unlike __syncthreads / S_BARRIER opcode). "memory"
// clobber stops the compiler from moving LDS/global ops across it.
__device__ __forceinline__ void wg_barrier() { asm volatile("s_barrier" ::: "memory"); }
// s_waitcnt imm: vmcnt[3:0] | expcnt<<4 | lgkmcnt<<8 | vmcnt[5:4]<<14
#define WAITCNT_VM4 0xF74  // vmcnt(4), lgkm/exp unconstrained
#define WAITCNT_VM0 0xF70  // vmcnt(0)

// ---------------- cast x (fp32) -> bf16 ----------------
__global__ __launch_bounds__(256) void cast_bf16_kernel(const float* __restrict__ x,
                                                        u16* __restrict__ o, int n4) {
  int i = blockIdx.x * 256 + threadIdx.x;
  if (i >= n4) return;
  v4f v = reinterpret_cast<const v4f*>(x)[i];
  u16x4 r;
  #pragma unroll
  for (int c = 0; c < 4; c++) r[c] = f2bf(v[c]);
  reinterpret_cast<u16x4*>(o)[i] = r;
}

// ---------------- transpose + cast W[k][n] -> Wt[n][k] bf16 ----------------
// z==0 (Wq) folds in the attention scale 1/sqrt(HD)*log2(e): Q leaves the QKV
// GEMM pre-scaled for the exp2-domain softmax (flash staging is a pure copy).
__global__ __launch_bounds__(256) void transpose_cast_kernel(const float* __restrict__ W0,
                                                             const float* __restrict__ W1,
                                                             const float* __restrict__ W2,
                                                             const float* __restrict__ W3,
                                                             u16* __restrict__ out) {
  const float* W = blockIdx.z == 0 ? W0 : blockIdx.z == 1 ? W1 : blockIdx.z == 2 ? W2 : W3;
  const float scale = (blockIdx.z == 0) ? 0.18033688011112042f : 1.0f;
  u16* T = out + (size_t)blockIdx.z * DIM * DIM;
  __shared__ float tile[32][33];
  int tx = threadIdx.x & 31, ty = threadIdx.x >> 5;
  int bn = blockIdx.x * 32, bk = blockIdx.y * 32;
  #pragma unroll
  for (int r = 0; r < 4; r++) {
    int k = bk + ty + r * 8;
    tile[ty + r * 8][tx] = W[(size_t)k * DIM + bn + tx];
  }
  __syncthreads();
  #pragma unroll
  for (int r = 0; r < 4; r++) {
    int n = bn + ty + r * 8;
    T[(size_t)n * DIM + bk + tx] = f2bf(tile[tx][ty + r * 8] * scale);
  }
}

// ======== 3-stage pipelined GEMM core (128x128 block, BK=32, raw-barrier) ========
// Workgroup-shared staging: per iter each wave issues 4 gll16 (1KB each) covering
// A 128x32 + B 128x32 into LDS stage buffer (i+2)%3. Consume order per iter i:
//   s_waitcnt vmcnt(4)  -- tile i (staged 2 iters ago) landed; tile i+1 in flight
//   raw s_barrier       -- all waves' tile-i loads landed; prev reads of buf(i+2)%3 done
//   issue stage(i+2)    -- prefetch depth 2 iterations (~2 MFMA phases of latency cover)
//   ds_read + 16 MFMA on tile i
// LDS buffer layout (16B chunks): chunk = rowgroup*64 + kchunk*16 + (m&15);
// gll16 dest contiguous in lane order. XCD swizzle: flat = x + 8y; xcd = flat&7
// owns an 8-panel M-slab x all N (per-XCD L2 ~ 2MB A-slab + 2MB W).

#define STAGE(s, kofs)                                                            \
  gll16(Ag0 + (kofs), Aw0 + (s) * 4096); gll16(Ag1 + (kofs), Aw1 + (s) * 4096);   \
  gll16(Bg0 + (kofs), Bw0 + (s) * 4096); gll16(Bg1 + (kofs), Bw1 + (s) * 4096);

#define COMPUTE(s)                                                                \
  { s8v af[4], bfv[4];                                                            \
    _Pragma("unroll") for (int i = 0; i < 4; i++)                                 \
      af[i] = *(const s8v*)(Al + (s) * 4096 + abase + i * 512);                   \
    _Pragma("unroll") for (int j = 0; j < 4; j++)                                 \
      bfv[j] = *(const s8v*)(Bl + (s) * 4096 + bbase + j * 512);                  \
    _Pragma("unroll") for (int i = 0; i < 4; i++)                                 \
      _Pragma("unroll") for (int j = 0; j < 4; j++)                               \
        acc[i][j] = __builtin_amdgcn_mfma_f32_16x16x32_bf16(af[i], bfv[j],        \
                                                            acc[i][j], 0, 0, 0); }

#define PIPE_STEP(s, nbuf, knext)                                                 \
  __builtin_amdgcn_s_waitcnt(WAITCNT_VM4);                                        \
  wg_barrier();                                                                   \
  STAGE(nbuf, knext)                                                              \
  COMPUTE(s)

#define GEMM_SETUP_AND_LOOP()                                                     \
  const int flat = blockIdx.x + 8 * blockIdx.y;                                   \
  const int xcd = flat & 7, slot = flat >> 3;                                     \
  const int m0 = (xcd * 8 + (slot & 7)) * 128;                                    \
  const int n0 = (slot >> 3) * 128;                                               \
  const int t = threadIdx.x;                                                      \
  const int lane = t & 63, w = t >> 6;                                            \
  const int waveM = w >> 1, waveN = w & 1;                                        \
  const int quad = lane >> 4, l16 = lane & 15;                                    \
  __shared__ u16 Al[12288];                                                       \
  __shared__ u16 Bl[12288];                                                       \
  v4f acc[4][4];                                                                  \
  _Pragma("unroll") for (int i = 0; i < 4; i++)                                   \
    _Pragma("unroll") for (int j = 0; j < 4; j++)                                 \
      acc[i][j] = (v4f){0.f, 0.f, 0.f, 0.f};                                      \
  const int sR = lane & 15, sC = lane >> 4;                                       \
  const u16* Ag0 = A  + (size_t)(m0 + (w * 2 + 0) * 16 + sR) * DIM + sC * 8;      \
  const u16* Ag1 = A  + (size_t)(m0 + (w * 2 + 1) * 16 + sR) * DIM + sC * 8;      \
  const u16* Bg0 = Bt + (size_t)(n0 + (w * 2 + 0) * 16 + sR) * DIM + sC * 8;      \
  const u16* Bg1 = Bt + (size_t)(n0 + (w * 2 + 1) * 16 + sR) * DIM + sC * 8;      \
  u16* Aw0 = Al + (w * 2 + 0) * 512;                                              \
  u16* Aw1 = Al + (w * 2 + 1) * 512;                                              \
  u16* Bw0 = Bl + (w * 2 + 0) * 512;                                              \
  u16* Bw1 = Bl + (w * 2 + 1) * 512;                                              \
  const int abase = waveM * 2048 + quad * 128 + l16 * 8;                          \
  const int bbase = waveN * 2048 + quad * 128 + l16 * 8;                          \
  STAGE(0, 0)                                                                     \
  STAGE(1, 32)                                                                    \
  for (int i3 = 0; i3 < 10; i3++) {                                               \
    const int kb = i3 * 96;                                                       \
    PIPE_STEP(0, 2, kb + 64)                                                      \
    PIPE_STEP(1, 0, kb + 96)                                                      \
    PIPE_STEP(2, 1, kb + 128)                                                     \
  }                                                                               \
  __builtin_amdgcn_s_waitcnt(WAITCNT_VM4);                                        \
  wg_barrier();                                                                   \
  COMPUTE(0)                                                                      \
  __builtin_amdgcn_s_waitcnt(WAITCNT_VM0);                                        \
  wg_barrier();                                                                   \
  COMPUTE(1)

// ---------------- fused QKV GEMM; z=0 -> Q (pre-scaled), z=1 -> K, z=2 -> V transposed ----------------
__global__ __launch_bounds__(256, 3) void gemm_qkv(const u16* __restrict__ A, const u16* __restrict__ Wt,
                                                   u16* __restrict__ Qb, u16* __restrict__ Kb,
                                                   u16* __restrict__ Vtg) {
  const int z = blockIdx.z;
  const u16* Bt = Wt + (size_t)z * DIM * DIM;
  GEMM_SETUP_AND_LOOP()
  if (z == 2) {
    // write V transposed: Vtg[((b*NH+h)*HD+d)*SEQ + s]
    #pragma unroll
    for (int i = 0; i < 4; i++) {
      #pragma unroll
      for (int j = 0; j < 4; j++) {
        int gm0 = m0 + waveM * 64 + i * 16 + quad * 4;
        int gn = n0 + waveN * 64 + j * 16 + l16;
        int b = gm0 >> 11, s0 = gm0 & (SEQ - 1), hh = gn >> 6, d = gn & (HD - 1);
        u16x4 o;
        #pragma unroll
        for (int r = 0; r < 4; r++) o[r] = f2bf(acc[i][j][r]);
        *(u16x4*)(Vtg + ((size_t)(b * NH + hh) * HD + d) * SEQ + s0) = o;
      }
    }
  } else {
    u16* C = (z == 0) ? Qb : Kb;
    #pragma unroll
    for (int i = 0; i < 4; i++) {
      #pragma unroll
      for (int j = 0; j < 4; j++) {
        int gn = n0 + waveN * 64 + j * 16 + l16;
        #pragma unroll
        for (int r = 0; r < 4; r++) {
          int gm = m0 + waveM * 64 + i * 16 + quad * 4 + r;
          C[(size_t)gm * DIM + gn] = f2bf(acc[i][j][r]);
        }
      }
    }
  }
}

// ---------------- projection GEMM: out = ctx * Wo^T + bias (fp32 out) ----------------
__global__ __launch_bounds__(256, 3) void gemm_proj(const u16* __restrict__ A, const u16* __restrict__ Bt,
                                                    float* __restrict__ Cf, const float* __restrict__ bias) {
  GEMM_SETUP_AND_LOOP()
  #pragma unroll
  for (int i = 0; i < 4; i++) {
    #pragma unroll
    for (int j = 0; j < 4; j++) {
      int gn = n0 + waveN * 64 + j * 16 + l16;
      float bv = bias[gn];
      #pragma unroll
      for (int r = 0; r < 4; r++) {
        int gm = m0 + waveM * 64 + i * 16 + quad * 4 + r;
        Cf[(size_t)gm * DIM + gn] = acc[i][j][r] + bv;
      }
    }
  }
}

// ---------------- MFMA flash attention (causal), transposed scores (R4 known-good) ----------------
// S^T = K*Q^T (K rows permuted so P^T registers are directly the PV B-fragment).
// Softmax over kv: 16 in-register values + 2 shfl_xor. O^T = Vt*P^T in C-layout.
// Causal balance: block pair {px, 15-px} -> 34 KV-tiles each. Grid (NH, px, BSZ).
__global__ __launch_bounds__(256, 3) void flash_attn_mfma(const u16* __restrict__ Qb,
                                                          const u16* __restrict__ Kb,
                                                          const u16* __restrict__ Vtg,
                                                          u16* __restrict__ Ob) {
  const int h = blockIdx.x, px = blockIdx.y, bb = blockIdx.z;
  const int t = threadIdx.x;
  const int lane = t & 63, w = t >> 6;
  const int quad = lane >> 4, l16 = lane & 15;

  __shared__ u16 QPs[QT * PAD];  // Q staging, then O^T epilogue bounce
  __shared__ u16 Ks[KT * PAD];   // K tile, rows permuted by pi^-1
  __shared__ u16 Vs[HD * PAD];   // V tile, [d][kv]

  const size_t qkbase = (size_t)bb * SEQ * DIM + h * HD;
  const size_t vbase = ((size_t)bb * NH + h) * (size_t)HD * SEQ;

  const int vrow = t >> 2, scol = (t & 3) * 16;
  const int krow = ((vrow >> 5) + 2 * ((vrow >> 2) & 1)) * 16 + ((vrow >> 3) & 3) * 4 + (vrow & 3);

  for (int pass = 0; pass < 2; pass++) {
    const int qi = (pass == 0) ? px : (SEQ / QT - 1 - px);
    const int q0 = qi * QT;
    const int wq = q0 + w * 32;
    const int ntiles = 2 * qi + 2;

    __syncthreads();  // QPs free (previous pass epilogue complete)

    // stage Q (pure copy; scale folded into Wq)
    {
      const int r = t >> 1, c0 = (t & 1) * 32;
      const u16* src = Qb + qkbase + (size_t)(q0 + r) * DIM + c0;
      #pragma unroll
      for (int ch = 0; ch < 4; ch++)
        *(u16x8*)(QPs + r * PAD + c0 + ch * 8) = *(const u16x8*)(src + ch * 8);
    }
    __syncthreads();

    // Q B-fragments: B[n=q][k=d]
    s8v qf[2][2];
    #pragma unroll
    for (int ni = 0; ni < 2; ni++)
      #pragma unroll
      for (int kc = 0; kc < 2; kc++)
        qf[ni][kc] = *(const s8v*)(QPs + (w * 32 + ni * 16 + l16) * PAD + kc * 32 + quad * 8);

    // preload KV tile 0 into registers
    u16x8 kr0, kr1, vr0, vr1;
    {
      const u16* kp = Kb + qkbase + (size_t)vrow * DIM + scol;
      kr0 = *(const u16x8*)kp; kr1 = *(const u16x8*)(kp + 8);
      const u16* vp = Vtg + vbase + (size_t)vrow * SEQ + scol;
      vr0 = *(const u16x8*)vp; vr1 = *(const u16x8*)(vp + 8);
    }

    float mrun[2] = {-1e30f, -1e30f}, lrun[2] = {0.f, 0.f};
    v4f O[4][2];
    #pragma unroll
    for (int di = 0; di < 4; di++)
      #pragma unroll
      for (int ni = 0; ni < 2; ni++) O[di][ni] = (v4f){0.f, 0.f, 0.f, 0.f};

    for (int it = 0; it < ntiles; ++it) {
      const int kv0 = it * KT;
      __syncthreads();
      *(u16x8*)(Ks + krow * PAD + scol) = kr0;
      *(u16x8*)(Ks + krow * PAD + scol + 8) = kr1;
      *(u16x8*)(Vs + vrow * PAD + scol) = vr0;
      *(u16x8*)(Vs + vrow * PAD + scol + 8) = vr1;
      __syncthreads();
      if (it + 1 < ntiles) {  // prefetch next tile (consumed after next barrier)
        const int nkv = kv0 + KT;
        const u16* kp = Kb + qkbase + (size_t)(nkv + vrow) * DIM + scol;
        kr0 = *(const u16x8*)kp; kr1 = *(const u16x8*)(kp + 8);
        const u16* vp = Vtg + vbase + (size_t)vrow * SEQ + nkv + scol;
        vr0 = *(const u16x8*)vp; vr1 = *(const u16x8*)(vp + 8);
      }
      if (kv0 > wq + 31) continue;  // tile fully masked for this wave

      // ---- S^T = K*Q^T : sc[mi][ni], rows kv (permuted), cols q ----
      v4f sc[4][2];
      #pragma unroll
      for (int mi = 0; mi < 4; mi++)
        #pragma unroll
        for (int ni = 0; ni < 2; ni++) sc[mi][ni] = (v4f){0.f, 0.f, 0.f, 0.f};
      #pragma unroll
      for (int kc = 0; kc < 2; kc++) {
        #pragma unroll
        for (int mi = 0; mi < 4; mi++) {
          s8v kf = *(const s8v*)(Ks + (mi * 16 + l16) * PAD + kc * 32 + quad * 8);
          sc[mi][0] = __builtin_amdgcn_mfma_f32_16x16x32_bf16(kf, qf[0][kc], sc[mi][0], 0, 0, 0);
          sc[mi][1] = __builtin_amdgcn_mfma_f32_16x16x32_bf16(kf, qf[1][kc], sc[mi][1], 0, 0, 0);
        }
      }

      // ---- causal mask: kv_g = kv0 + (mi&1)*32 + quad*8 + (mi>>1)*4 + r ----
      if (kv0 + KT > wq) {
        #pragma unroll
        for (int mi = 0; mi < 4; mi++) {
          const int kvb = kv0 + (mi & 1) * 32 + quad * 8 + (mi >> 1) * 4;
          #pragma unroll
          for (int ni = 0; ni < 2; ni++) {
            const int qg = wq + ni * 16 + l16;
            #pragma unroll
            for (int r = 0; r < 4; r++)
              if (kvb + r > qg) sc[mi][ni][r] = -1e30f;
          }
        }
      }

      // ---- online softmax: per lane 16 kv values, 2 shuffles per reduce ----
      float alpha[2];
      #pragma unroll
      for (int ni = 0; ni < 2; ni++) {
        float mx = -1e30f;
        #pragma unroll
        for (int mi = 0; mi < 4; mi++)
          #pragma unroll
          for (int r = 0; r < 4; r++) mx = fmaxf(mx, sc[mi][ni][r]);
        mx = fmaxf(mx, __shfl_xor(mx, 16, 64));
        mx = fmaxf(mx, __shfl_xor(mx, 32, 64));
        const float mnew = fmaxf(mrun[ni], mx);
        alpha[ni] = fast_exp2(mrun[ni] - mnew);
        mrun[ni] = mnew;
        float rsum = 0.f;
        #pragma unroll
        for (int mi = 0; mi < 4; mi++)
          #pragma unroll
          for (int r = 0; r < 4; r++) {
            float p = fast_exp2(sc[mi][ni][r] - mnew);
            sc[mi][ni][r] = p;
            rsum += p;
          }
        rsum += __shfl_xor(rsum, 16, 64);
        rsum += __shfl_xor(rsum, 32, 64);
        lrun[ni] = lrun[ni] * alpha[ni] + rsum;
      }
      #pragma unroll
      for (int di = 0; di < 4; di++)
        #pragma unroll
        for (int ni = 0; ni < 2; ni++)
          #pragma unroll
          for (int r = 0; r < 4; r++) O[di][ni][r] *= alpha[ni];

      // ---- pack P^T as PV B-frag: pf[ni][kc][j] = P[q][kv=kc*32+quad*8+j] ----
      s8v pf[2][2];
      #pragma unroll
      for (int ni = 0; ni < 2; ni++)
        #pragma unroll
        for (int kc = 0; kc < 2; kc++)
          #pragma unroll
          for (int j = 0; j < 8; j++)
            pf[ni][kc][j] = (short)f2bf(sc[kc + 2 * (j >> 2)][ni][j & 3]);

      // ---- PV: O^T[d][q] += Vt * P^T ----
      #pragma unroll
      for (int kc = 0; kc < 2; kc++) {
        #pragma unroll
        for (int di = 0; di < 4; di++) {
          s8v vf = *(const s8v*)(Vs + (di * 16 + l16) * PAD + kc * 32 + quad * 8);
          O[di][0] = __builtin_amdgcn_mfma_f32_16x16x32_bf16(vf, pf[0][kc], O[di][0], 0, 0, 0);
          O[di][1] = __builtin_amdgcn_mfma_f32_16x16x32_bf16(vf, pf[1][kc], O[di][1], 0, 0, 0);
        }
      }
    }

    // ---- epilogue: normalize, transpose via LDS (wave-private rows), coalesced write ----
    const float inv0 = 1.f / lrun[0], inv1 = 1.f / lrun[1];
    #pragma unroll
    for (int di = 0; di < 4; di++)
      #pragma unroll
      for (int ni = 0; ni < 2; ni++) {
        const float inv = ni ? inv1 : inv0;
        #pragma unroll
        for (int r = 0; r < 4; r++)
          QPs[(w * 32 + ni * 16 + l16) * PAD + di * 16 + quad * 4 + r] = f2bf(O[di][ni][r] * inv);
      }
    __syncthreads();
    {
      const int r = t >> 1, c0 = (t & 1) * 32;
      u16* dst = Ob + qkbase + (size_t)(q0 + r) * DIM + c0;
      #pragma unroll
      for (int ch = 0; ch < 4; ch++)
        *(u16x8*)(dst + ch * 8) = *(const u16x8*)(QPs + r * PAD + c0 + ch * 8);
    }
  }
}

// ---------------- launch ----------------
extern "C" void kernel_launch(void* const* d_in, const int* in_sizes, int n_in,
                              void* d_out, int out_size, void* d_ws, size_t ws_size,
                              hipStream_t stream) {
  (void)in_sizes; (void)n_in; (void)out_size; (void)ws_size;
  const float* x  = (const float*)d_in[0];
  const float* Wq = (const float*)d_in[1];
  const float* Wk = (const float*)d_in[2];
  const float* Wv = (const float*)d_in[3];
  const float* Wo = (const float*)d_in[4];
  const float* bo = (const float*)d_in[5];
  float* out = (float*)d_out;

  char* ws = (char*)d_ws;
  const size_t MB = 1024ull * 1024ull;
  u16* Xb  = (u16*)(ws);             // 16 MB: x bf16 [8192][1024]
  u16* Wt  = (u16*)(ws + 16 * MB);   //  8 MB: Wq(scaled),Wk,Wv,Wo transposed bf16
  u16* Qb  = (u16*)(ws + 24 * MB);   // 16 MB
  u16* Kb  = (u16*)(ws + 40 * MB);   // 16 MB
  u16* Vtg = (u16*)(ws + 56 * MB);   // 16 MB: V transposed [b][h][d][s]
  u16* Cb  = (u16*)(ws + 72 * MB);   // 16 MB: ctx -> 88 MB total

  const int NTOK = BSZ * SEQ;  // 8192
  const int n4 = NTOK * DIM / 4;
  cast_bf16_kernel<<<(n4 + 255) / 256, 256, 0, stream>>>(x, Xb, n4);
  transpose_cast_kernel<<<dim3(32, 32, 4), 256, 0, stream>>>(Wq, Wk, Wv, Wo, Wt);

  gemm_qkv<<<dim3(DIM / 128, NTOK / 128, 3), 256, 0, stream>>>(Xb, Wt, Qb, Kb, Vtg);

  flash_attn_mfma<<<dim3(NH, SEQ / QT / 2, BSZ), 256, 0, stream>>>(Qb, Kb, Vtg, Cb);

  gemm_proj<<<dim3(DIM / 128, NTOK / 128), 256, 0, stream>>>(Cb, Wt + 3ull * DIM * DIM, out, bo);
}